// Round 17
// baseline (94.191 us; speedup 1.0000x reference)
//
#include <hip/hip_runtime.h>
#include <hip/hip_bf16.h>
#include <cstddef>

// B=8, L=1024, E=1024, H=8, d=128
// out = BandedGaussianAttn(values @ Win^T) @ Wout^T
// Identity (R4..R16-proven): equal stds -> smoothing commutes with projection;
// per-head offset = row shift of GEMM1's A operand (BN=128 == one head).
// R17: smoother FUSED into GEMM1's A-staging (reg-staged fp32 -> 9-tap -> bf16
//      ds_write, swizzled). Pipeline: wcvt -> gemm1_smooth -> GEMM2 (R16-exact).

#define BATCH 8
#define SEQL  1024
#define EMB   1024

typedef unsigned short u16;
typedef __attribute__((ext_vector_type(8))) short s16x8;
typedef __attribute__((ext_vector_type(4))) float f32x4;
typedef __attribute__((ext_vector_type(8))) unsigned short u16x8;
typedef __attribute__((ext_vector_type(4))) unsigned short u16x4;

#define GLOAD_LDS16(g, l)                                                     \
    __builtin_amdgcn_global_load_lds(                                         \
        (const __attribute__((address_space(1))) void*)(g),                   \
        (__attribute__((address_space(3))) void*)(l), 16, 0, 0)

__device__ __forceinline__ u16 f2bf(float f) {
    unsigned u = __builtin_bit_cast(unsigned, f);
    u += 0x7FFF + ((u >> 16) & 1);
    return (u16)(u >> 16);
}

__constant__ int c_ofs[8] = { -3, -2, -1, 0, 0, 1, 2, 3 };

// ---------- wcvt: Win/Wout fp32 -> bf16 ----------
__global__ __launch_bounds__(256) void wcvt(
    const float* __restrict__ wi, const float* __restrict__ wo,
    u16* __restrict__ wib, u16* __restrict__ wob)
{
    const int k = blockIdx.x * 256 + threadIdx.x;        // 0..262143
    const float* src = (k < 131072) ? wi : wo;
    u16* dst = (k < 131072) ? wib : wob;
    const size_t off = (size_t)(k & 131071) * 8;
    const float4 a = *(const float4*)(src + off);
    const float4 b4 = *(const float4*)(src + off + 4);
    u16x8 o;
    o[0] = f2bf(a.x);  o[1] = f2bf(a.y);  o[2] = f2bf(a.z);  o[3] = f2bf(a.w);
    o[4] = f2bf(b4.x); o[5] = f2bf(b4.y); o[6] = f2bf(b4.z); o[7] = f2bf(b4.w);
    *(u16x8*)(dst + off) = o;
}

constexpr int BM = 256, BN = 128, BK = 64;
constexpr int A_EL = BM * BK;
constexpr int B_EL = BN * BK;
constexpr int BUF_EL = A_EL + B_EL;      // 48 KB x3 = 144 KB

// ---------- gemm1_smooth: Attb = smooth(values)[shifted rows] @ Winb^T ----------
// A-side: reg-staged fp32 loads (16 covering rows/thread, issued at phase0),
// 9-tap fp32 smoothing + swizzled bf16 ds_write at phase1. B-side: gload_lds
// from Winb (R16 pattern). vmcnt: auto-wait on xr (A newer than B(t+1)) +
// explicit vmcnt(2) keeps only B(t+2) in flight.
__global__ __launch_bounds__(512, 2) void gemm1_smooth(
    const float* __restrict__ values, const unsigned char* __restrict__ mask,
    const u16* __restrict__ Bw, u16* __restrict__ Cout)
{
    constexpr float W[9] = {
        1.3383022576488537e-04f, 4.431848411938008e-03f, 5.399096651318806e-02f,
        2.4197072451914337e-01f, 3.989422804014327e-01f, 2.4197072451914337e-01f,
        5.399096651318806e-02f,  4.431848411938008e-03f, 1.3383022576488537e-04f
    };
    __shared__ u16 lds[3 * BUF_EL];

    const int tid  = threadIdx.x;
    const int lane = tid & 63;
    const int wave = tid >> 6;
    const int K = EMB, N = EMB;

    const int nwg = gridDim.x;
    const int bid = blockIdx.x;
    const int swz = (bid & 7) * (nwg >> 3) + (bid >> 3);   // T1 bijective
    const int ntn = N >> 7;
    const int row0 = (swz / ntn) * BM;
    const int col0 = (swz % ntn) * BN;

    const int b  = row0 >> 10;               // BM=256 | 1024: no batch straddle
    const int q0 = row0 & (SEQL - 1);
    const int rb = q0 + c_ofs[col0 >> 7];    // raw base (batch-relative)

    const u16* Bb = Bw + (size_t)col0 * K;

    const int wm = wave >> 1;
    const int wn = wave & 1;
    const int fr = lane & 15;
    const int fg = lane >> 4;

    const int srow   = tid >> 3;             // B-staging coords (R16)
    const int schunk = tid & 7;

    // A-staging coords: thread = (rowgrp 0..31) x (colgrp 0..15), 8 rows x 4 cols
    const int rowgrp = tid >> 4;
    const int colgrp = tid & 15;
    const int r0s = rowgrp * 8;
    const float* vsrc = values + (size_t)b * SEQL * EMB + colgrp * 4;
    const unsigned char* mrow = mask + b * SEQL;

    int   voff[16];
    float fH[16];
    #pragma unroll
    for (int i = 0; i < 16; ++i) {           // covering raw rows r0s-4 .. r0s+11
        const int praw = rb + r0s - 4 + i;
        const int vc = praw < 0 ? 0 : (praw > SEQL - 1 ? SEQL - 1 : praw);
        voff[i] = vc;
        fH[i] = ((unsigned)praw < (unsigned)SEQL && !mrow[vc]) ? 1.f : 0.f;
    }

    f32x4 acc[4][4] = {};
    f32x4 xr[16];
    s16x8 af[4][2], bf0[2][2], bf1[2][2];

    auto loadA = [&](int kt) {               // 16 fp32x4 into xr (issue-early)
        const int k0 = kt << 6;
        #pragma unroll
        for (int i = 0; i < 16; ++i)
            xr[i] = *(const f32x4*)(vsrc + (size_t)voff[i] * EMB + k0);
    };
    auto stageB = [&](int bsel, int kt) {
        u16* Bdst = lds + bsel * BUF_EL + A_EL;
        const int k0 = kt << 6;
        #pragma unroll
        for (int c = 0; c < 2; ++c) {
            const int row = c * 64 + srow;
            const int sc  = (schunk ^ (row & 7)) << 3;
            GLOAD_LDS16(Bb + (size_t)row * K + k0 + sc, Bdst + c * 4096 + wave * 512);
        }
    };
    auto smoothWrite = [&](int bsel) {       // consume xr -> swizzled bf16 A-tile
        u16* Adst = lds + bsel * BUF_EL;
        #pragma unroll
        for (int i = 0; i < 16; ++i) {       // auto-waits the xr loads
            xr[i][0] *= fH[i]; xr[i][1] *= fH[i];
            xr[i][2] *= fH[i]; xr[i][3] *= fH[i];
        }
        #pragma unroll
        for (int k = 0; k < 8; ++k) {
            f32x4 s = {};
            #pragma unroll
            for (int j = 0; j < 9; ++j) {
                const float w = W[j];
                s[0] = fmaf(w, xr[k + j][0], s[0]);
                s[1] = fmaf(w, xr[k + j][1], s[1]);
                s[2] = fmaf(w, xr[k + j][2], s[2]);
                s[3] = fmaf(w, xr[k + j][3], s[3]);
            }
            u16x4 o;
            o[0] = f2bf(s[0]); o[1] = f2bf(s[1]); o[2] = f2bf(s[2]); o[3] = f2bf(s[3]);
            const int rout = r0s + k;
            const int slot = (colgrp >> 1) ^ (rout & 7);
            *(u16x4*)(Adst + rout * 64 + slot * 8 + (colgrp & 1) * 4) = o;
        }
    };

    auto phase0 = [&](int tile, bool doStage) {
        const u16* Abuf = lds + (tile % 3) * BUF_EL;
        const u16* Bbuf = Abuf + A_EL;
        #pragma unroll
        for (int m = 0; m < 4; ++m)
            #pragma unroll
            for (int kk = 0; kk < 2; ++kk) {
                const int row = wm * 64 + m * 16 + fr;
                const int ch  = ((kk << 2) + fg) ^ (row & 7);
                af[m][kk] = *(const s16x8*)(Abuf + row * 64 + ch * 8);
            }
        #pragma unroll
        for (int n = 0; n < 2; ++n)
            #pragma unroll
            for (int kk = 0; kk < 2; ++kk) {
                const int row = wn * 64 + n * 16 + fr;
                const int ch  = ((kk << 2) + fg) ^ (row & 7);
                bf0[n][kk] = *(const s16x8*)(Bbuf + row * 64 + ch * 8);
            }
        if (doStage) { loadA(tile + 2); stageB((tile + 2) % 3, tile + 2); }
        __builtin_amdgcn_s_barrier();
        asm volatile("s_waitcnt lgkmcnt(0)" ::: "memory");
        __builtin_amdgcn_sched_barrier(0);
        __builtin_amdgcn_s_setprio(1);
        #pragma unroll
        for (int m = 0; m < 4; ++m)
            #pragma unroll
            for (int n = 0; n < 2; ++n)
                #pragma unroll
                for (int kk = 0; kk < 2; ++kk)
                    acc[m][n] = __builtin_amdgcn_mfma_f32_16x16x32_bf16(
                        af[m][kk], bf0[n][kk], acc[m][n], 0, 0, 0);
        __builtin_amdgcn_s_setprio(0);
        __builtin_amdgcn_s_barrier();
    };

    auto phase1 = [&](int tile, int mode /*0: smooth+write+vm2, 1: vm0, 2: none*/) {
        const u16* Abuf = lds + (tile % 3) * BUF_EL;
        const u16* Bbuf = Abuf + A_EL;
        #pragma unroll
        for (int n = 0; n < 2; ++n)
            #pragma unroll
            for (int kk = 0; kk < 2; ++kk) {
                const int row = wn * 64 + (2 + n) * 16 + fr;
                const int ch  = ((kk << 2) + fg) ^ (row & 7);
                bf1[n][kk] = *(const s16x8*)(Bbuf + row * 64 + ch * 8);
            }
        if (mode == 0) {
            smoothWrite((tile + 2) % 3);     // buffer (t-1)%3: readers done @t-1
            asm volatile("s_waitcnt vmcnt(2)" ::: "memory");   // only B(t+2) in flight
        } else if (mode == 1) {
            asm volatile("s_waitcnt vmcnt(0)" ::: "memory");
        }
        __builtin_amdgcn_s_barrier();
        asm volatile("s_waitcnt lgkmcnt(0)" ::: "memory");
        __builtin_amdgcn_sched_barrier(0);
        __builtin_amdgcn_s_setprio(1);
        #pragma unroll
        for (int m = 0; m < 4; ++m)
            #pragma unroll
            for (int n = 0; n < 2; ++n)
                #pragma unroll
                for (int kk = 0; kk < 2; ++kk)
                    acc[m][2 + n] = __builtin_amdgcn_mfma_f32_16x16x32_bf16(
                        af[m][kk], bf1[n][kk], acc[m][2 + n], 0, 0, 0);
        __builtin_amdgcn_s_setprio(0);
        __builtin_amdgcn_s_barrier();
    };

    const int NT = K >> 6;                   // 16

    // prologue: fill buffers 0 and 1
    loadA(0); stageB(0, 0);
    smoothWrite(0);                          // auto-wait drains A(0) loads
    loadA(1); stageB(1, 1);
    smoothWrite(1);                          // drains A(1); B(0) older -> done
    asm volatile("s_waitcnt vmcnt(2)" ::: "memory");    // B(0) resident
    asm volatile("s_waitcnt lgkmcnt(0)" ::: "memory");  // A-writes drained
    __builtin_amdgcn_s_barrier();

    for (int t = 0; t < NT - 2; ++t) { phase0(t, true); phase1(t, 0); }
    phase0(NT - 2, false); phase1(NT - 2, 1);
    phase0(NT - 1, false); phase1(NT - 1, 2);

    const int crow0 = row0 + wm * 64 + fg * 4;
    const int ccol0 = col0 + wn * 64 + fr;
    u16* C = Cout;
    #pragma unroll
    for (int m = 0; m < 4; ++m)
        #pragma unroll
        for (int n = 0; n < 4; ++n)
            #pragma unroll
            for (int j = 0; j < 4; ++j)
                C[(size_t)(crow0 + m * 16 + j) * N + ccol0 + n * 16] =
                    f2bf(acc[m][n][j]);
}

// ---------- GEMM2: R16-exact pipelined bf16 MFMA GEMM ----------
__global__ __launch_bounds__(512, 2) void gemm_nt_pipe(
    const u16* __restrict__ A, const u16* __restrict__ B,
    float* __restrict__ Cout, int M, int N, int K)
{
    __shared__ u16 lds[3 * BUF_EL];

    const int tid  = threadIdx.x;
    const int lane = tid & 63;
    const int wave = tid >> 6;

    const int nwg = gridDim.x;
    const int bid = blockIdx.x;
    const int swz = (bid & 7) * (nwg >> 3) + (bid >> 3);
    const int ntn = N >> 7;
    const int row0 = (swz / ntn) * BM;
    const int col0 = (swz % ntn) * BN;

    const u16* Ab = A + (size_t)row0 * K;
    const u16* Bb = B + (size_t)col0 * K;

    const int wm = wave >> 1;
    const int wn = wave & 1;
    const int fr = lane & 15;
    const int fg = lane >> 4;

    const int srow   = tid >> 3;
    const int schunk = tid & 7;

    f32x4 acc[4][4] = {};
    s16x8 af[4][2], bf0[2][2], bf1[2][2];

    auto stageA3 = [&](int bsel, int kt) {
        u16* Abuf = lds + bsel * BUF_EL;
        const int k0 = kt << 6;
        #pragma unroll
        for (int c = 0; c < 3; ++c) {
            const int row = c * 64 + srow;
            const int sc  = (schunk ^ (row & 7)) << 3;
            GLOAD_LDS16(Ab + (size_t)row * K + k0 + sc, Abuf + c * 4096 + wave * 512);
        }
    };
    auto stageRest = [&](int bsel, int kt) {
        u16* Abuf = lds + bsel * BUF_EL;
        u16* Bbuf = Abuf + A_EL;
        const int k0 = kt << 6;
        {
            const int row = 192 + srow;
            const int sc  = (schunk ^ (row & 7)) << 3;
            GLOAD_LDS16(Ab + (size_t)row * K + k0 + sc, Abuf + 3 * 4096 + wave * 512);
        }
        #pragma unroll
        for (int c = 0; c < 2; ++c) {
            const int row = c * 64 + srow;
            const int sc  = (schunk ^ (row & 7)) << 3;
            GLOAD_LDS16(Bb + (size_t)row * K + k0 + sc, Bbuf + c * 4096 + wave * 512);
        }
    };

    auto phase0 = [&](int tile, bool doStage) {
        const u16* Abuf = lds + (tile % 3) * BUF_EL;
        const u16* Bbuf = Abuf + A_EL;
        #pragma unroll
        for (int m = 0; m < 4; ++m)
            #pragma unroll
            for (int kk = 0; kk < 2; ++kk) {
                const int row = wm * 64 + m * 16 + fr;
                const int ch  = ((kk << 2) + fg) ^ (row & 7);
                af[m][kk] = *(const s16x8*)(Abuf + row * 64 + ch * 8);
            }
        #pragma unroll
        for (int n = 0; n < 2; ++n)
            #pragma unroll
            for (int kk = 0; kk < 2; ++kk) {
                const int row = wn * 64 + n * 16 + fr;
                const int ch  = ((kk << 2) + fg) ^ (row & 7);
                bf0[n][kk] = *(const s16x8*)(Bbuf + row * 64 + ch * 8);
            }
        if (doStage) stageA3((tile + 2) % 3, tile + 2);
        __builtin_amdgcn_s_barrier();
        asm volatile("s_waitcnt lgkmcnt(0)" ::: "memory");
        __builtin_amdgcn_sched_barrier(0);
        __builtin_amdgcn_s_setprio(1);
        #pragma unroll
        for (int m = 0; m < 4; ++m)
            #pragma unroll
            for (int n = 0; n < 2; ++n)
                #pragma unroll
                for (int kk = 0; kk < 2; ++kk)
                    acc[m][n] = __builtin_amdgcn_mfma_f32_16x16x32_bf16(
                        af[m][kk], bf0[n][kk], acc[m][n], 0, 0, 0);
        __builtin_amdgcn_s_setprio(0);
        __builtin_amdgcn_s_barrier();
    };

    auto phase1 = [&](int tile, int mode) {
        const u16* Abuf = lds + (tile % 3) * BUF_EL;
        const u16* Bbuf = Abuf + A_EL;
        #pragma unroll
        for (int n = 0; n < 2; ++n)
            #pragma unroll
            for (int kk = 0; kk < 2; ++kk) {
                const int row = wn * 64 + (2 + n) * 16 + fr;
                const int ch  = ((kk << 2) + fg) ^ (row & 7);
                bf1[n][kk] = *(const s16x8*)(Bbuf + row * 64 + ch * 8);
            }
        if (mode == 0) {
            stageRest((tile + 2) % 3, tile + 2);
            asm volatile("s_waitcnt vmcnt(6)" ::: "memory");
        } else if (mode == 1) {
            asm volatile("s_waitcnt vmcnt(0)" ::: "memory");
        }
        __builtin_amdgcn_s_barrier();
        asm volatile("s_waitcnt lgkmcnt(0)" ::: "memory");
        __builtin_amdgcn_sched_barrier(0);
        __builtin_amdgcn_s_setprio(1);
        #pragma unroll
        for (int m = 0; m < 4; ++m)
            #pragma unroll
            for (int n = 0; n < 2; ++n)
                #pragma unroll
                for (int kk = 0; kk < 2; ++kk)
                    acc[m][2 + n] = __builtin_amdgcn_mfma_f32_16x16x32_bf16(
                        af[m][kk], bf1[n][kk], acc[m][2 + n], 0, 0, 0);
        __builtin_amdgcn_s_setprio(0);
        __builtin_amdgcn_s_barrier();
    };

    const int NT = K >> 6;

    stageA3(0, 0); stageRest(0, 0);
    stageA3(1, 1); stageRest(1, 1);
    asm volatile("s_waitcnt vmcnt(6)" ::: "memory");
    __builtin_amdgcn_s_barrier();

    for (int t = 0; t < NT - 2; ++t) { phase0(t, true); phase1(t, 0); }
    phase0(NT - 2, false); phase1(NT - 2, 1);
    phase0(NT - 1, false); phase1(NT - 1, 2);

    const int crow0 = row0 + wm * 64 + fg * 4;
    const int ccol0 = col0 + wn * 64 + fr;
    #pragma unroll
    for (int m = 0; m < 4; ++m)
        #pragma unroll
        for (int n = 0; n < 4; ++n)
            #pragma unroll
            for (int j = 0; j < 4; ++j)
                Cout[(size_t)(crow0 + m * 16 + j) * N + ccol0 + n * 16] =
                    acc[m][n][j];
}

extern "C" void kernel_launch(void* const* d_in, const int* in_sizes, int n_in,
                              void* d_out, int out_size, void* d_ws, size_t ws_size,
                              hipStream_t stream) {
    const float* values = (const float*)d_in[0];
    // d_in[1] = queries: only its length matters (Lq == L)
    const unsigned char* mask = (const unsigned char*)d_in[2];
    const float* Win  = (const float*)d_in[3];
    const float* Wout = (const float*)d_in[4];
    float* out = (float*)d_out;

    const int M = BATCH * SEQL;   // 8192
    const int N = EMB;            // 1024
    const int K = EMB;            // 1024

    u16* Attb  = (u16*)d_ws;                              // 16 MB
    u16* Winb  = Attb + (size_t)M * EMB;                  // 2 MB
    u16* Woutb = Winb + (size_t)EMB * EMB;                // 2 MB (20 MB total)

    wcvt<<<1024, 256, 0, stream>>>(Win, Wout, Winb, Woutb);

    dim3 ggrid((M / BM) * (N / BN));   // 256 WGs
    gemm1_smooth<<<ggrid, 512, 0, stream>>>(values, mask, Winb, Attb);
    gemm_nt_pipe<<<ggrid, 512, 0, stream>>>(Attb, Woutb, out, M, N, K);
}

// Round 18
// 61.318 us; speedup vs baseline: 1.5361x; 1.5361x over previous
//
#include <hip/hip_runtime.h>
#include <hip/hip_bf16.h>
#include <cstddef>

// B=8, L=1024, E=1024, H=8, d=128
// out = BandedGaussianAttn(values @ Win^T) @ Wout^T
// FINAL (R13/R16 config, best verified: 61.0 us, absmax 0.0156):
//   Identity: equal per-head stds -> gaussian attention = 9-tap smoothing
//   (commutes with the value projection); per-head offset = row shift of
//   GEMM1's A operand selected by output column block (BN=128 == one head).
//   smooth_lds: async-staged (global_load_lds x10) 9-tap fp32 smoother
//               -> bf16 VG, + Win/Wout bf16 cvt in tail blocks
//   GEMM1: Attb = VG(shifted rows) @ Winb^T  (bf16 MFMA 16x16x32)
//   GEMM2: out  = Attb @ Woutb^T             (bf16 in, fp32 out)
//   GEMM structure: BM=256 BN=128 BK=64, 512thr/8waves (4Mx2N), 3-buffer LDS,
//   2 fine phases/K-tile, counted vmcnt(6) (never 0 in main loop), T2
//   both-sides XOR swizzle, T5 setprio around MFMA, T1 bijective XCD swizzle.

#define BATCH 8
#define SEQL  1024
#define EMB   1024
#define VROWS 1056   // 33 x 32; VG row r holds smoothed source p = r-4

typedef unsigned short u16;
typedef __attribute__((ext_vector_type(8))) short s16x8;
typedef __attribute__((ext_vector_type(4))) float f32x4;
typedef __attribute__((ext_vector_type(8))) unsigned short u16x8;
typedef __attribute__((ext_vector_type(4))) unsigned short u16x4;

#define GLOAD_LDS16(g, l)                                                     \
    __builtin_amdgcn_global_load_lds(                                         \
        (const __attribute__((address_space(1))) void*)(g),                   \
        (__attribute__((address_space(3))) void*)(l), 16, 0, 0)

__device__ __forceinline__ u16 f2bf(float f) {
    unsigned u = __builtin_bit_cast(unsigned, f);
    u += 0x7FFF + ((u >> 16) & 1);
    return (u16)(u >> 16);
}

__constant__ int c_ofs[8] = { -3, -2, -1, 0, 0, 1, 2, 3 };

// ---------- smooth_lds: async-staged 9-tap smoother ----------
__global__ __launch_bounds__(256) void smooth_lds(
    const float* __restrict__ values, const unsigned char* __restrict__ mask,
    const float* __restrict__ wi, const float* __restrict__ wo,
    u16* __restrict__ VG, u16* __restrict__ wib, u16* __restrict__ wob)
{
    constexpr float W[9] = {
        1.3383022576488537e-04f, 4.431848411938008e-03f, 5.399096651318806e-02f,
        2.4197072451914337e-01f, 3.989422804014327e-01f, 2.4197072451914337e-01f,
        5.399096651318806e-02f,  4.431848411938008e-03f, 1.3383022576488537e-04f
    };
    __shared__ float sx[40 * 256];
    __shared__ float smf[40];

    const int blk = blockIdx.x;
    const int NSM = BATCH * 33 * 4;    // 1056
    const int tid = threadIdx.x;
    if (blk < NSM) {
        const int b  = blk & 7;
        const int t  = blk >> 3;
        const int g  = t >> 2;
        const int cg = t & 3;
        const int r0 = g * 32;
        const int v0 = r0 - 8;
        const int c0 = cg * 256;
        const float* vbase = values + (size_t)b * SEQL * EMB + c0;
        const unsigned char* mrow = mask + b * SEQL;

        #pragma unroll
        for (int c = 0; c < 10; ++c) {
            const int n    = c * 256 + tid;
            const int row  = n >> 6;
            const int col4 = (n & 63) * 4;
            const int v    = v0 + row;
            const int vc   = v < 0 ? 0 : (v > SEQL - 1 ? SEQL - 1 : v);
            GLOAD_LDS16(vbase + (size_t)vc * EMB + col4,
                        sx + c * 1024 + (tid >> 6) * 256);
        }
        if (tid < 40) {
            const int v  = v0 + tid;
            const int vc = v < 0 ? 0 : (v > SEQL - 1 ? SEQL - 1 : v);
            smf[tid] = ((unsigned)v < (unsigned)SEQL && !mrow[vc]) ? 1.f : 0.f;
        }
        asm volatile("s_waitcnt vmcnt(0)" ::: "memory");
        __syncthreads();

        const int rg = tid >> 6;
        const int cc = tid & 63;
        const int rl0 = rg * 8;
        f32x4 acc[8] = {};
        #pragma unroll
        for (int i = 0; i < 16; ++i) {
            const f32x4 xr = *(const f32x4*)&sx[(rl0 + i) * 256 + cc * 4];
            const float f = smf[rl0 + i];
            const float x0 = xr[0] * f, x1 = xr[1] * f, x2 = xr[2] * f, x3 = xr[3] * f;
            #pragma unroll
            for (int k = 0; k < 8; ++k) {
                const int j = i - k;
                if (j < 0 || j > 8) continue;
                const float w = W[j];
                acc[k][0] = fmaf(w, x0, acc[k][0]);
                acc[k][1] = fmaf(w, x1, acc[k][1]);
                acc[k][2] = fmaf(w, x2, acc[k][2]);
                acc[k][3] = fmaf(w, x3, acc[k][3]);
            }
        }
        u16* og = VG + (size_t)(b * VROWS + r0 + rl0) * EMB + c0 + cc * 4;
        #pragma unroll
        for (int k = 0; k < 8; ++k) {
            u16x4 o;
            o[0] = f2bf(acc[k][0]); o[1] = f2bf(acc[k][1]);
            o[2] = f2bf(acc[k][2]); o[3] = f2bf(acc[k][3]);
            *(u16x4*)(og + (size_t)k * EMB) = o;
        }
    } else {
        const int k = (blk - NSM) * 256 + tid;
        const float* src = (k < 131072) ? wi : wo;
        u16* dst = (k < 131072) ? wib : wob;
        const size_t off = (size_t)(k & 131071) * 8;
        const float4 a = *(const float4*)(src + off);
        const float4 b4 = *(const float4*)(src + off + 4);
        u16x8 o;
        o[0] = f2bf(a.x);  o[1] = f2bf(a.y);  o[2] = f2bf(a.z);  o[3] = f2bf(a.w);
        o[4] = f2bf(b4.x); o[5] = f2bf(b4.y); o[6] = f2bf(b4.z); o[7] = f2bf(b4.w);
        *(u16x8*)(dst + off) = o;
    }
}

// ---------- pipelined bf16 MFMA GEMM: C[M,N] = A[M,K]*B[N,K]^T ----------
constexpr int BM = 256, BN = 128, BK = 64;
constexpr int A_EL = BM * BK;
constexpr int B_EL = BN * BK;
constexpr int BUF_EL = A_EL + B_EL;      // 48 KB x3 = 144 KB

template <bool OUT_BF16, bool SHIFTED>
__global__ __launch_bounds__(512, 2) void gemm_nt_pipe(
    const u16* __restrict__ A, const u16* __restrict__ B,
    void* __restrict__ Cout, int M, int N, int K)
{
    __shared__ u16 lds[3 * BUF_EL];

    const int tid  = threadIdx.x;
    const int lane = tid & 63;
    const int wave = tid >> 6;

    const int nwg = gridDim.x;
    const int bid = blockIdx.x;
    const int swz = (bid & 7) * (nwg >> 3) + (bid >> 3);
    const int ntn = N >> 7;
    const int row0 = (swz / ntn) * BM;
    const int col0 = (swz % ntn) * BN;

    int arow0;
    if (SHIFTED) {
        const int b  = row0 >> 10;            // BM=256 | 1024: no batch straddle
        const int q0 = row0 & (SEQL - 1);
        arow0 = b * VROWS + q0 + 4 + c_ofs[col0 >> 7];
    } else {
        arow0 = row0;
    }
    const u16* Ab = A + (size_t)arow0 * K;
    const u16* Bb = B + (size_t)col0 * K;

    const int wm = wave >> 1;
    const int wn = wave & 1;
    const int fr = lane & 15;
    const int fg = lane >> 4;

    const int srow   = tid >> 3;
    const int schunk = tid & 7;

    f32x4 acc[4][4] = {};
    s16x8 af[4][2], bf0[2][2], bf1[2][2];

    auto stageA3 = [&](int bsel, int kt) {
        u16* Abuf = lds + bsel * BUF_EL;
        const int k0 = kt << 6;
        #pragma unroll
        for (int c = 0; c < 3; ++c) {
            const int row = c * 64 + srow;
            const int sc  = (schunk ^ (row & 7)) << 3;
            GLOAD_LDS16(Ab + (size_t)row * K + k0 + sc, Abuf + c * 4096 + wave * 512);
        }
    };
    auto stageRest = [&](int bsel, int kt) {
        u16* Abuf = lds + bsel * BUF_EL;
        u16* Bbuf = Abuf + A_EL;
        const int k0 = kt << 6;
        {
            const int row = 192 + srow;
            const int sc  = (schunk ^ (row & 7)) << 3;
            GLOAD_LDS16(Ab + (size_t)row * K + k0 + sc, Abuf + 3 * 4096 + wave * 512);
        }
        #pragma unroll
        for (int c = 0; c < 2; ++c) {
            const int row = c * 64 + srow;
            const int sc  = (schunk ^ (row & 7)) << 3;
            GLOAD_LDS16(Bb + (size_t)row * K + k0 + sc, Bbuf + c * 4096 + wave * 512);
        }
    };

    auto phase0 = [&](int tile, bool doStage) {
        const u16* Abuf = lds + (tile % 3) * BUF_EL;
        const u16* Bbuf = Abuf + A_EL;
        #pragma unroll
        for (int m = 0; m < 4; ++m)
            #pragma unroll
            for (int kk = 0; kk < 2; ++kk) {
                const int row = wm * 64 + m * 16 + fr;
                const int ch  = ((kk << 2) + fg) ^ (row & 7);
                af[m][kk] = *(const s16x8*)(Abuf + row * 64 + ch * 8);
            }
        #pragma unroll
        for (int n = 0; n < 2; ++n)
            #pragma unroll
            for (int kk = 0; kk < 2; ++kk) {
                const int row = wn * 64 + n * 16 + fr;
                const int ch  = ((kk << 2) + fg) ^ (row & 7);
                bf0[n][kk] = *(const s16x8*)(Bbuf + row * 64 + ch * 8);
            }
        if (doStage) stageA3((tile + 2) % 3, tile + 2);
        __builtin_amdgcn_s_barrier();
        asm volatile("s_waitcnt lgkmcnt(0)" ::: "memory");
        __builtin_amdgcn_sched_barrier(0);
        __builtin_amdgcn_s_setprio(1);
        #pragma unroll
        for (int m = 0; m < 4; ++m)
            #pragma unroll
            for (int n = 0; n < 2; ++n)
                #pragma unroll
                for (int kk = 0; kk < 2; ++kk)
                    acc[m][n] = __builtin_amdgcn_mfma_f32_16x16x32_bf16(
                        af[m][kk], bf0[n][kk], acc[m][n], 0, 0, 0);
        __builtin_amdgcn_s_setprio(0);
        __builtin_amdgcn_s_barrier();
    };

    auto phase1 = [&](int tile, int mode /*0: stage+vm6, 1: vm0, 2: none*/) {
        const u16* Abuf = lds + (tile % 3) * BUF_EL;
        const u16* Bbuf = Abuf + A_EL;
        #pragma unroll
        for (int n = 0; n < 2; ++n)
            #pragma unroll
            for (int kk = 0; kk < 2; ++kk) {
                const int row = wn * 64 + (2 + n) * 16 + fr;
                const int ch  = ((kk << 2) + fg) ^ (row & 7);
                bf1[n][kk] = *(const s16x8*)(Bbuf + row * 64 + ch * 8);
            }
        if (mode == 0) {
            stageRest((tile + 2) % 3, tile + 2);
            asm volatile("s_waitcnt vmcnt(6)" ::: "memory");
        } else if (mode == 1) {
            asm volatile("s_waitcnt vmcnt(0)" ::: "memory");
        }
        __builtin_amdgcn_s_barrier();
        asm volatile("s_waitcnt lgkmcnt(0)" ::: "memory");
        __builtin_amdgcn_sched_barrier(0);
        __builtin_amdgcn_s_setprio(1);
        #pragma unroll
        for (int m = 0; m < 4; ++m)
            #pragma unroll
            for (int n = 0; n < 2; ++n)
                #pragma unroll
                for (int kk = 0; kk < 2; ++kk)
                    acc[m][2 + n] = __builtin_amdgcn_mfma_f32_16x16x32_bf16(
                        af[m][kk], bf1[n][kk], acc[m][2 + n], 0, 0, 0);
        __builtin_amdgcn_s_setprio(0);
        __builtin_amdgcn_s_barrier();
    };

    const int NT = K >> 6;

    stageA3(0, 0); stageRest(0, 0);
    stageA3(1, 1); stageRest(1, 1);
    asm volatile("s_waitcnt vmcnt(6)" ::: "memory");
    __builtin_amdgcn_s_barrier();

    for (int t = 0; t < NT - 2; ++t) { phase0(t, true); phase1(t, 0); }
    phase0(NT - 2, false); phase1(NT - 2, 1);
    phase0(NT - 1, false); phase1(NT - 1, 2);

    const int crow0 = row0 + wm * 64 + fg * 4;
    const int ccol0 = col0 + wn * 64 + fr;
    if (OUT_BF16) {
        u16* C = (u16*)Cout;
        #pragma unroll
        for (int m = 0; m < 4; ++m)
            #pragma unroll
            for (int n = 0; n < 4; ++n)
                #pragma unroll
                for (int j = 0; j < 4; ++j)
                    C[(size_t)(crow0 + m * 16 + j) * N + ccol0 + n * 16] =
                        f2bf(acc[m][n][j]);
    } else {
        float* C = (float*)Cout;
        #pragma unroll
        for (int m = 0; m < 4; ++m)
            #pragma unroll
            for (int n = 0; n < 4; ++n)
                #pragma unroll
                for (int j = 0; j < 4; ++j)
                    C[(size_t)(crow0 + m * 16 + j) * N + ccol0 + n * 16] =
                        acc[m][n][j];
    }
}

extern "C" void kernel_launch(void* const* d_in, const int* in_sizes, int n_in,
                              void* d_out, int out_size, void* d_ws, size_t ws_size,
                              hipStream_t stream) {
    const float* values = (const float*)d_in[0];
    // d_in[1] = queries: only its length matters (Lq == L)
    const unsigned char* mask = (const unsigned char*)d_in[2];
    const float* Win  = (const float*)d_in[3];
    const float* Wout = (const float*)d_in[4];
    float* out = (float*)d_out;

    const int M = BATCH * SEQL;   // 8192
    const int N = EMB;            // 1024
    const int K = EMB;            // 1024

    u16* VG    = (u16*)d_ws;                              // 8*1056*1024 (17.3 MB)
    u16* Attb  = VG + (size_t)BATCH * VROWS * EMB;        // 16 MB
    u16* Winb  = Attb + (size_t)M * EMB;                  // 2 MB
    u16* Woutb = Winb + (size_t)EMB * EMB;                // 2 MB (~37 MB total)

    smooth_lds<<<1056 + 1024, 256, 0, stream>>>(
        values, mask, Win, Wout, VG, Winb, Woutb);

    dim3 ggrid((M / BM) * (N / BN));   // 256 WGs
    gemm_nt_pipe<true,  true ><<<ggrid, 512, 0, stream>>>(VG,   Winb,  Attb, M, N, K);
    gemm_nt_pipe<false, false><<<ggrid, 512, 0, stream>>>(Attb, Woutb, out,  M, N, K);
}